// Round 15
// baseline (148.732 us; speedup 1.0000x reference)
//
#include <hip/hip_runtime.h>
#include <stdint.h>

#define DIM    128
#define HEADS  8
#define INNER  1024
#define HIDDEN 512
#define BATCH  8
#define SEQ    1024
#define ROWS   8192   // BATCH*SEQ

typedef __attribute__((ext_vector_type(8))) short bf16x8;
typedef __attribute__((ext_vector_type(4))) float f32x4;
typedef __attribute__((ext_vector_type(16))) float f32x16;
typedef __attribute__((ext_vector_type(4))) unsigned short u16x4;

// q is pre-scaled by 1/sqrt(128) * log2(e) so attention works in exp2 domain
#define QSCALE (0.08838834764831845f * 1.4426950408889634f)

#define AS1 __attribute__((address_space(1)))
#define AS3 __attribute__((address_space(3)))

static __device__ __forceinline__ float b2f(unsigned short u) {
    union { float f; unsigned int i; } v; v.i = ((unsigned int)u) << 16; return v.f;
}
static __device__ __forceinline__ unsigned short f2b(float f) {
    union { float f; unsigned int i; } v; v.f = f;
    unsigned int x = v.i;
    return (unsigned short)((x + 0x7fffu + ((x >> 16) & 1u)) >> 16);
}
static __device__ __forceinline__ unsigned int cvt_pk_bf16(float a, float b) {
    unsigned int r;
    asm("v_cvt_pk_bf16_f32 %0, %1, %2" : "=v"(r) : "v"(a), "v"(b));
    return r;
}
// async global->LDS, 16B per lane; LDS dest is wave-uniform base + lane*16
static __device__ __forceinline__ void gl_lds16(const unsigned short* g, unsigned short* l) {
    __builtin_amdgcn_global_load_lds((AS1 void*)g, (AS3 void*)l, 16, 0, 0);
}

// MFMA A-fragment ("PA") layout: lane-linear 1KB blocks per (row-tile, k-chunk).
static __device__ __forceinline__ size_t pa_idx(int row, int k, int K) {
    return ((size_t)((row >> 4) * (K >> 5) + (k >> 5)) << 9)
         + (size_t)(((((k >> 3) & 3) << 4) + (row & 15)) << 3) + (size_t)(k & 7);
}

// ---------------- weight f32 -> bf16 + permute to PA layout ----------------
template<int K>
static __device__ __forceinline__ void cvtw(const float* __restrict__ W,
                                            unsigned short* __restrict__ Wp, int j)
{
    const int c  = j & 15;
    const int gw = (j >> 4) & 3;
    const int blk = j >> 6;
    const int ks = blk & ((K >> 5) - 1);
    const int nt = blk / (K >> 5);
    const int n  = nt * 16 + c;
    const int kb = ks * 32 + gw * 8;
    const float4 a = *(const float4*)(W + (size_t)n * K + kb);
    const float4 b = *(const float4*)(W + (size_t)n * K + kb + 4);
    u16x4 o0, o1;
    o0[0] = f2b(a.x); o0[1] = f2b(a.y); o0[2] = f2b(a.z); o0[3] = f2b(a.w);
    o1[0] = f2b(b.x); o1[1] = f2b(b.y); o1[2] = f2b(b.z); o1[3] = f2b(b.w);
    *(u16x4*)(Wp + (size_t)j * 8)     = o0;
    *(u16x4*)(Wp + (size_t)j * 8 + 4) = o1;
}

__global__ __launch_bounds__(256)
void cvt_all_kernel(const float* __restrict__ s0, unsigned short* __restrict__ d0,
                    const float* __restrict__ s1, unsigned short* __restrict__ d1,
                    const float* __restrict__ s2, unsigned short* __restrict__ d2,
                    const float* __restrict__ s3, unsigned short* __restrict__ d3,
                    const float* __restrict__ s4, unsigned short* __restrict__ d4)
{
    int j = blockIdx.x * 256 + threadIdx.x;
    if (j < 16384)                 { cvtw<128>(s0, d0, j);  return; }
    if ((j -= 16384) < 32768)      { cvtw<128>(s1, d1, j);  return; }
    if ((j -= 32768) < 16384)      { cvtw<1024>(s2, d2, j); return; }
    if ((j -= 16384) < 8192)       { cvtw<128>(s3, d3, j);  return; }
    j -= 8192;                       cvtw<512>(s4, d4, j);
}

// ---------------- LayerNorm (x and y): f32 row-major in, bf16 PA(128) out ----------------
static __device__ __forceinline__ void ln_row(const float* __restrict__ in,
                                              const float* __restrict__ w,
                                              const float* __restrict__ b,
                                              unsigned short* __restrict__ out,
                                              int row, int lane)
{
    const float2 xv = *(const float2*)(in + (size_t)row*DIM + lane*2);
    float x0 = xv.x, x1 = xv.y;
    float s = x0 + x1;
    float q = x0*x0 + x1*x1;
    #pragma unroll
    for (int off = 32; off > 0; off >>= 1) {
        s += __shfl_xor(s, off);
        q += __shfl_xor(q, off);
    }
    const float mu  = s * (1.0f/128.0f);
    const float var = q * (1.0f/128.0f) - mu*mu;
    const float rs  = rsqrtf(var + 1e-5f);
    const float2 wv = *(const float2*)(w + lane*2);
    const float2 bv = *(const float2*)(b + lane*2);
    unsigned short o0 = f2b((x0 - mu) * rs * wv.x + bv.x);
    unsigned short o1 = f2b((x1 - mu) * rs * wv.y + bv.y);
    *(unsigned int*)(out + pa_idx(row, lane*2, 128)) = (unsigned int)o0 | ((unsigned int)o1 << 16);
}

__global__ __launch_bounds__(256)
void ln_dual_kernel(const float* __restrict__ inx, const float* __restrict__ wx,
                    const float* __restrict__ bx, unsigned short* __restrict__ outx,
                    const float* __restrict__ iny, const float* __restrict__ wy,
                    const float* __restrict__ by, unsigned short* __restrict__ outy)
{
    const int row  = blockIdx.x * 4 + (threadIdx.x >> 6);
    const int lane = threadIdx.x & 63;
    if (blockIdx.y == 0) ln_row(inx, wx, bx, outx, row, lane);
    else                 ln_row(iny, wy, by, outy, row, lane);
}

// ---------------- merged q + kv projection GEMM (one launch, vectorized stores) ----------------
// blockIdx.x: 0..15 -> q (swapped operands), 16..31 -> K (swapped), 32..47 -> V (normal)
// K layout per bh,chunk(32m): elem = chunk*4096 + (d>>4)*512 + ((d>>3)&1)*256 + (m&31)*8 + (d&7)
// V layout per bh,chunk(32m): elem = chunk*4096 + ((p>>5)*2 + ((m>>4)&1))*512 + ((m>>3)&1)*256 + (p&31)*8 + (m&7)
__global__ __launch_bounds__(256)
void qkv_kernel(const unsigned short* __restrict__ xn,  // PA(128)
                const unsigned short* __restrict__ yn,  // PA(128)
                const unsigned short* __restrict__ wq,  // PA(128), 1024 rows
                const unsigned short* __restrict__ wkv, // PA(128), 2048 rows
                unsigned short* __restrict__ qb,
                unsigned short* __restrict__ kpm,
                unsigned short* __restrict__ vpm)
{
    const int lane = threadIdx.x & 63;
    const int wave = threadIdx.x >> 6;
    const int g    = lane >> 4;
    const int c16  = lane & 15;
    const int bx   = blockIdx.x;
    const int by   = blockIdx.y;

    f32x4 acc[4];
    #pragma unroll
    for (int t = 0; t < 4; ++t) acc[t] = (f32x4){0.f, 0.f, 0.f, 0.f};

    if (bx < 32) {
        // ---- swapped: A = weight tile (rows of D), B = activation tile (cols of D) ----
        const bool isq = bx < 16;
        const unsigned short* W = isq ? wq : wkv;
        const unsigned short* Aact = isq ? xn : yn;
        const int wt = (bx & 15) * 4 + wave;           // weight tile (16 rows each)
        #pragma unroll
        for (int ks = 0; ks < 4; ++ks) {
            bf16x8 wf = *(const bf16x8*)(W + (((size_t)(wt*4 + ks)) << 9) + lane*8);
            #pragma unroll
            for (int t = 0; t < 4; ++t) {
                bf16x8 af = *(const bf16x8*)(Aact + (((size_t)((by*4 + t)*4 + ks)) << 9) + lane*8);
                acc[t] = __builtin_amdgcn_mfma_f32_16x16x32_bf16(wf, af, acc[t], 0, 0, 0);
            }
        }
        const int n_w0 = (bx & 15)*64 + wave*16 + g*4;  // weight row (p/d dim), r walks +1
        const int hh = n_w0 >> 7;
        const int p0 = n_w0 & 127;
        #pragma unroll
        for (int t = 0; t < 4; ++t) {
            const int m_row = by*64 + t*16 + c16;
            const int bb = m_row >> 10, m = m_row & 1023;
            u16x4 o;
            if (isq) {
                o[0] = f2b(acc[t][0]*QSCALE); o[1] = f2b(acc[t][1]*QSCALE);
                o[2] = f2b(acc[t][2]*QSCALE); o[3] = f2b(acc[t][3]*QSCALE);
                *(u16x4*)&qb[(((size_t)(bb*HEADS + hh))*SEQ + m)*DIM + p0] = o;
            } else {
                o[0] = f2b(acc[t][0]); o[1] = f2b(acc[t][1]);
                o[2] = f2b(acc[t][2]); o[3] = f2b(acc[t][3]);
                const int chunk = m >> 5;
                const int ds = p0 >> 4, dhi = (p0 >> 3) & 1, de = p0 & 7;
                *(u16x4*)&kpm[(size_t)(bb*HEADS + hh)*SEQ*DIM
                    + (size_t)(chunk*4096 + ds*512 + dhi*256 + (m & 31)*8 + de)] = o;
            }
        }
    } else {
        // ---- normal: V half (weight rows 1024..2047 of wkv) ----
        const int mt = by*4 + wave;
        #pragma unroll
        for (int ks = 0; ks < 4; ++ks) {
            bf16x8 af = *(const bf16x8*)(yn + (((size_t)(mt*4 + ks)) << 9) + lane*8);
            #pragma unroll
            for (int t = 0; t < 4; ++t) {
                const int nt = 64 + (bx - 32)*4 + t;
                bf16x8 wf = *(const bf16x8*)(wkv + (((size_t)(nt*4 + ks)) << 9) + lane*8);
                acc[t] = __builtin_amdgcn_mfma_f32_16x16x32_bf16(af, wf, acc[t], 0, 0, 0);
            }
        }
        const int m_row0 = by*64 + wave*16 + g*4;       // seq row, r walks +1
        const int bb = m_row0 >> 10;
        const int m0 = m_row0 & 1023;
        const int chunk = m0 >> 5, s = (m0 >> 4) & 1, mhi = (m0 >> 3) & 1, e0 = m0 & 7;
        #pragma unroll
        for (int t = 0; t < 4; ++t) {
            const int p = (bx - 32)*64 + t*16 + c16;
            const int hh = p >> 7, pp = p & 127, pt = pp >> 5, pc = pp & 31;
            u16x4 o;
            o[0] = f2b(acc[t][0]); o[1] = f2b(acc[t][1]);
            o[2] = f2b(acc[t][2]); o[3] = f2b(acc[t][3]);
            *(u16x4*)&vpm[(size_t)(bb*HEADS + hh)*SEQ*DIM
                + (size_t)(chunk*4096 + (pt*2 + s)*512 + mhi*256 + pc*8 + e0)] = o;
        }
    }
}

// ---------------- Flash attention v9: 4 waves x 32 q-rows, 32x32 MFMA, in-register P ----------------
__global__ __launch_bounds__(256)
void attn_kernel(const unsigned short* __restrict__ qbuf,  // (B,H,N,P) pre-scaled
                 const unsigned short* __restrict__ kperm, // per bh: [chunk][4096] (A-frag linear)
                 const unsigned short* __restrict__ vperm, // per bh: [chunk][4096] (B-frag linear)
                 unsigned short* __restrict__ obuf)        // PA(1024) over rows (B*SEQ)
{
    __shared__ unsigned short kbuf[2][4096];   // 8KB per chunk
    __shared__ unsigned short vbuf[2][4096];

    const int lane = threadIdx.x & 63;
    const int wave = threadIdx.x >> 6;         // 0..3
    const int l31  = lane & 31;
    const int hi   = lane >> 5;

    // XCD swizzle: all 8 q-blocks of one bh land on the same XCD (j%8)
    const int j    = blockIdx.x;
    const int bh   = (j & 7) * 8 + (j >> 6);
    const int nblk = (j >> 3) & 7;
    const int n0   = nblk * 128 + wave * 32;
    const int bb   = bh >> 3, hh = bh & 7;

    const unsigned short* Q  = qbuf  + (size_t)bh * SEQ * DIM;
    const unsigned short* Kb = kperm + (size_t)bh * SEQ * DIM;
    const unsigned short* Vb = vperm + (size_t)bh * SEQ * DIM;

    // stage chunk 0: wave w covers K segs {2w,2w+1} and V segs {2w,2w+1} (1KB each)
    #pragma unroll
    for (int i = 0; i < 2; ++i) {
        gl_lds16(Kb + (wave*2 + i)*512 + lane*8, &kbuf[0][(wave*2 + i)*512]);
        gl_lds16(Vb + (wave*2 + i)*512 + lane*8, &vbuf[0][(wave*2 + i)*512]);
    }

    // Q B-fragments: lane holds Q[q=n0+l31][d = ds*16 + hi*8 + e]
    bf16x8 qf[8];
    #pragma unroll
    for (int ds = 0; ds < 8; ++ds)
        qf[ds] = *(const bf16x8*)(Q + (size_t)(n0 + l31)*DIM + ds*16 + hi*8);

    f32x16 oacc[4];
    #pragma unroll
    for (int pt = 0; pt < 4; ++pt)
        #pragma unroll
        for (int r = 0; r < 16; ++r) oacc[pt][r] = 0.f;
    float mi = 8.0f;              // row-uniform initial max guess (exp2 domain)
    float li0 = 0.f, li1 = 0.f;   // per-lane partials (q = l31)

    __syncthreads();   // chunk 0 staged

    int cur = 0;
    for (int it = 0; it < 32; ++it, cur ^= 1) {
        // ---- stage chunk it+1 (async; drains at the end-of-iter barrier) ----
        if (it != 31) {
            const unsigned short* Ks = Kb + (size_t)(it + 1) * 4096;
            const unsigned short* Vs = Vb + (size_t)(it + 1) * 4096;
            #pragma unroll
            for (int i = 0; i < 2; ++i) {
                gl_lds16(Ks + (wave*2 + i)*512 + lane*8, &kbuf[cur ^ 1][(wave*2 + i)*512]);
                gl_lds16(Vs + (wave*2 + i)*512 + lane*8, &vbuf[cur ^ 1][(wave*2 + i)*512]);
            }
        }

        // ---- QK^T: S^T[m][q], 8 MFMAs over d ----
        f32x16 st;
        #pragma unroll
        for (int r = 0; r < 16; ++r) st[r] = 0.f;
        #pragma unroll
        for (int ds = 0; ds < 8; ++ds) {
            bf16x8 kf = *(const bf16x8*)&kbuf[cur][ds*512 + lane*8];
            st = __builtin_amdgcn_mfma_f32_32x32x16_bf16(kf, qf[ds], st, 0, 0, 0);
        }

        // ---- V B-fragments (issued early; consumed after softmax) ----
        bf16x8 vf[8];   // f = pt*2 + s
        #pragma unroll
        for (int f = 0; f < 8; ++f)
            vf[f] = *(const bf16x8*)&vbuf[cur][f*512 + lane*8];

        // ---- softmax, fully per-lane in the common path (q = l31) ----
        float cmax = st[0];
        #pragma unroll
        for (int r = 1; r < 16; ++r) cmax = fmaxf(cmax, st[r]);

        if (!__all(cmax - mi <= 8.0f)) {   // rare rescale path
            float rmax = fmaxf(cmax, __shfl_xor(cmax, 32));
            const float mnew  = fmaxf(mi, rmax);
            const float alpha = exp2f(mi - mnew);
            mi = mnew;
            li0 *= alpha; li1 *= alpha;
            float ar[16];
            #pragma unroll
            for (int r = 0; r < 16; ++r)
                ar[r] = __shfl(alpha, (r & 3) + 8*(r >> 2) + 4*hi);
            #pragma unroll
            for (int pt = 0; pt < 4; ++pt)
                #pragma unroll
                for (int r = 0; r < 16; ++r) oacc[pt][r] *= ar[r];
        }

        float p[16];
        #pragma unroll
        for (int r = 0; r < 16; ++r) p[r] = exp2f(st[r] - mi);
        li0 += ((p[0]+p[1]) + (p[2]+p[3])) + ((p[4]+p[5]) + (p[6]+p[7]));
        li1 += ((p[8]+p[9]) + (p[10]+p[11])) + ((p[12]+p[13]) + (p[14]+p[15]));

        // ---- P -> A-fragments in-register (cvt_pk + shfl_xor32 + select) ----
        // target: pa[s] lane holds P[q=l31][m = s*16 + hi*8 + e], e=0..7
        union { unsigned w[4]; bf16x8 v; } pa0, pa1;
        {
            unsigned a0 = cvt_pk_bf16(p[0], p[1]),  a1 = cvt_pk_bf16(p[2], p[3]);
            unsigned b0 = cvt_pk_bf16(p[4], p[5]),  b1 = cvt_pk_bf16(p[6], p[7]);
            unsigned sa0 = __shfl_xor((int)a0, 32), sb0 = __shfl_xor((int)b0, 32);
            unsigned sa1 = __shfl_xor((int)a1, 32), sb1 = __shfl_xor((int)b1, 32);
            pa0.w[0] = hi ? sb0 : a0;
            pa0.w[1] = hi ? sb1 : a1;
            pa0.w[2] = hi ? b0  : sa0;
            pa0.w[3] = hi ? b1  : sa1;
        }
        {
            unsigned a0 = cvt_pk_bf16(p[8], p[9]),   a1 = cvt_pk_bf16(p[10], p[11]);
            unsigned b0 = cvt_pk_bf16(p[12], p[13]), b1 = cvt_pk_bf16(p[14], p[15]);
            unsigned sa0 = __shfl_xor((int)a0, 32), sb0 = __shfl_xor((int)b0, 32);
            unsigned sa1 = __shfl_xor((int)a1, 32), sb1 = __shfl_xor((int)b1, 32);
            pa1.w[0] = hi ? sb0 : a0;
            pa1.w[1] = hi ? sb1 : a1;
            pa1.w[2] = hi ? b0  : sa0;
            pa1.w[3] = hi ? b1  : sa1;
        }

        // ---- PV: oacc[pt] += P(s) x V(pt,s) ----
        #pragma unroll
        for (int pt = 0; pt < 4; ++pt) {
            oacc[pt] = __builtin_amdgcn_mfma_f32_32x32x16_bf16(pa0.v, vf[pt*2 + 0], oacc[pt], 0, 0, 0);
            oacc[pt] = __builtin_amdgcn_mfma_f32_32x32x16_bf16(pa1.v, vf[pt*2 + 1], oacc[pt], 0, 0, 0);
        }

        __syncthreads();   // stage(it+1) drained + all waves done with buf[cur]
    }

    // ---- epilogue: row sums, normalize, write PA(1024) ----
    float li = li0 + li1;
    li += __shfl_xor(li, 32);        // lanes l and l^32 share q and cover disjoint m
    const float inv = 1.f / li;
    float lrv[16];
    #pragma unroll
    for (int r = 0; r < 16; ++r)
        lrv[r] = __shfl(inv, (r & 3) + 8*(r >> 2) + 4*hi);

    #pragma unroll
    for (int pt = 0; pt < 4; ++pt)
        #pragma unroll
        for (int r = 0; r < 16; ++r) {
            const int qr  = (r & 3) + 8*(r >> 2) + 4*hi;
            const int row = bb*SEQ + n0 + qr;
            const int k   = hh*DIM + pt*32 + l31;
            obuf[pa_idx(row, k, INNER)] = f2b(oacc[pt][r] * lrv[r]);
        }
}

// ---------------- proj GEMM + bias + ls1*resid + LayerNorm fused ----------------
__global__ __launch_bounds__(256)
void projln_kernel(const unsigned short* __restrict__ A,   // ob PA(1024)
                   const unsigned short* __restrict__ W,   // wpr PA(1024), 128 rows
                   const float* __restrict__ bias,         // proj_b
                   const float* __restrict__ gamma,        // ls1_gamma
                   const float* __restrict__ xres,         // x (f32)
                   float* __restrict__ x1,                 // out: residual (f32)
                   const float* __restrict__ lnw, const float* __restrict__ lnb,
                   unsigned short* __restrict__ hin)       // out: PA(128)
{
    __shared__ float part[4][16][2];

    const int lane = threadIdx.x & 63;
    const int wave = threadIdx.x >> 6;
    const int g    = lane >> 4;
    const int c16  = lane & 15;
    const int mt   = blockIdx.x;

    f32x4 acc[2];
    acc[0] = (f32x4){0.f,0.f,0.f,0.f};
    acc[1] = (f32x4){0.f,0.f,0.f,0.f};

    #pragma unroll 4
    for (int ks = 0; ks < 32; ++ks) {
        bf16x8 af = *(const bf16x8*)(A + (((size_t)(mt*32 + ks)) << 9) + lane*8);
        #pragma unroll
        for (int t = 0; t < 2; ++t) {
            bf16x8 wf = *(const bf16x8*)(W + (((size_t)((wave*2 + t)*32 + ks)) << 9) + lane*8);
            acc[t] = __builtin_amdgcn_mfma_f32_16x16x32_bf16(af, wf, acc[t], 0, 0, 0);
        }
    }

    float v[2][4];
    #pragma unroll
    for (int t = 0; t < 2; ++t) {
        const int col = wave*32 + t*16 + c16;
        const float bb = bias[col], gg = gamma[col];
        #pragma unroll
        for (int r = 0; r < 4; ++r) {
            const int row = mt*16 + g*4 + r;
            const float xv = xres[(size_t)row*DIM + col];
            v[t][r] = xv + (acc[t][r] + bb) * gg;
            x1[(size_t)row*DIM + col] = v[t][r];
        }
    }
    #pragma unroll
    for (int r = 0; r < 4; ++r) {
        float s = v[0][r] + v[1][r];
        float q = v[0][r]*v[0][r] + v[1][r]*v[1][r];
        #pragma unroll
        for (int off = 1; off < 16; off <<= 1) {
            s += __shfl_xor(s, off);
            q += __shfl_xor(q, off);
        }
        if (c16 == 0) { part[wave][g*4+r][0] = s; part[wave][g*4+r][1] = q; }
    }
    __syncthreads();

    #pragma unroll
    for (int r = 0; r < 4; ++r) {
        const int lr = g*4 + r;
        const float s = part[0][lr][0] + part[1][lr][0] + part[2][lr][0] + part[3][lr][0];
        const float q = part[0][lr][1] + part[1][lr][1] + part[2][lr][1] + part[3][lr][1];
        const float mu  = s * (1.0f/128.0f);
        const float var = q * (1.0f/128.0f) - mu*mu;
        const float rs  = rsqrtf(var + 1e-5f);
        const int row = mt*16 + lr;
        #pragma unroll
        for (int t = 0; t < 2; ++t) {
            const int col = wave*32 + t*16 + c16;
            const float hv = (v[t][r] - mu) * rs * lnw[col] + lnb[col];
            hin[pa_idx(row, col, 128)] = f2b(hv);
        }
    }
}

// ---------------- fc1 + relu + fc2 + bias + ls2*resid fused ----------------
__global__ __launch_bounds__(256)
void fc_kernel(const unsigned short* __restrict__ hin,  // PA(128)
               const unsigned short* __restrict__ W1,   // PA(128), 512 rows
               const float* __restrict__ b1,
               const unsigned short* __restrict__ W2,   // PA(512), 128 rows
               const float* __restrict__ b2,
               const float* __restrict__ gamma2,        // ls2
               const float* __restrict__ x1,            // f32 residual
               float* __restrict__ dout)
{
    __shared__ unsigned short h[16][520];   // 512 + 8 pad

    const int lane = threadIdx.x & 63;
    const int wave = threadIdx.x >> 6;
    const int g    = lane >> 4;
    const int c16  = lane & 15;
    const int mt   = blockIdx.x;

    f32x4 a1[8];
    #pragma unroll
    for (int t = 0; t < 8; ++t) a1[t] = (f32x4){0.f,0.f,0.f,0.f};
    #pragma unroll
    for (int ks = 0; ks < 4; ++ks) {
        bf16x8 af = *(const bf16x8*)(hin + (((size_t)(mt*4 + ks)) << 9) + lane*8);
        #pragma unroll
        for (int t = 0; t < 8; ++t) {
            const int nt = wave*8 + t;
            bf16x8 wf = *(const bf16x8*)(W1 + (((size_t)(nt*4 + ks)) << 9) + lane*8);
            a1[t] = __builtin_amdgcn_mfma_f32_16x16x32_bf16(af, wf, a1[t], 0, 0, 0);
        }
    }
    #pragma unroll
    for (int t = 0; t < 8; ++t) {
        const int col = wave*128 + t*16 + c16;
        const float bb = b1[col];
        #pragma unroll
        for (int r = 0; r < 4; ++r)
            h[g*4 + r][col] = f2b(fmaxf(a1[t][r] + bb, 0.f));
    }
    __syncthreads();

    f32x4 a2[2];
    a2[0] = (f32x4){0.f,0.f,0.f,0.f};
    a2[1] = (f32x4){0.f,0.f,0.f,0.f};
    #pragma unroll 4
    for (int ks = 0; ks < 16; ++ks) {
        bf16x8 af = *(const bf16x8*)&h[c16][ks*32 + g*8];
        #pragma unroll
        for (int t = 0; t < 2; ++t) {
            const int nt = wave*2 + t;
            bf16x8 wf = *(const bf16x8*)(W2 + (((size_t)(nt*16 + ks)) << 9) + lane*8);
            a2[t] = __builtin_amdgcn_mfma_f32_16x16x32_bf16(af, wf, a2[t], 0, 0, 0);
        }
    }
    #pragma unroll
    for (int t = 0; t < 2; ++t) {
        const int col = wave*32 + t*16 + c16;
        const float bb = b2[col], gg = gamma2[col];
        #pragma unroll
        for (int r = 0; r < 4; ++r) {
            const int row = mt*16 + g*4 + r;
            dout[(size_t)row*DIM + col] = x1[(size_t)row*DIM + col] + (a2[t][r] + bb) * gg;
        }
    }
}

// ---------------- launch ----------------
extern "C" void kernel_launch(void* const* d_in, const int* in_sizes, int n_in,
                              void* d_out, int out_size, void* d_ws, size_t ws_size,
                              hipStream_t stream)
{
    const float* x         = (const float*)d_in[0];
    const float* y         = (const float*)d_in[1];
    const float* norm_x_w  = (const float*)d_in[2];
    const float* norm_x_b  = (const float*)d_in[3];
    const float* norm_y_w  = (const float*)d_in[4];
    const float* norm_y_b  = (const float*)d_in[5];
    const float* q_w       = (const float*)d_in[6];
    const float* kv_w      = (const float*)d_in[7];
    const float* proj_w    = (const float*)d_in[8];
    const float* proj_b    = (const float*)d_in[9];
    const float* ls1_gamma = (const float*)d_in[10];
    const float* norm_o_w  = (const float*)d_in[11];
    const float* norm_o_b  = (const float*)d_in[12];
    const float* fc1_w     = (const float*)d_in[13];
    const float* fc1_b     = (const float*)d_in[14];
    const float* fc2_w     = (const float*)d_in[15];
    const float* fc2_b     = (const float*)d_in[16];
    const float* ls2_gamma = (const float*)d_in[17];

    char* ws = (char*)d_ws;
    size_t off = 0;
    auto alloc = [&](size_t bytes) {
        void* p = ws + off;
        off += (bytes + 255) & ~(size_t)255;
        return p;
    };
    unsigned short* xn  = (unsigned short*)alloc((size_t)ROWS*DIM*2);
    unsigned short* yn  = (unsigned short*)alloc((size_t)ROWS*DIM*2);
    unsigned short* qb  = (unsigned short*)alloc((size_t)ROWS*INNER*2);
    unsigned short* kpm = (unsigned short*)alloc((size_t)ROWS*INNER*2);
    unsigned short* vpm = (unsigned short*)alloc((size_t)ROWS*INNER*2);
    unsigned short* ob  = (unsigned short*)alloc((size_t)ROWS*INNER*2);
    float*          x1  = (float*)alloc((size_t)ROWS*DIM*4);
    unsigned short* hin = (unsigned short*)alloc((size_t)ROWS*DIM*2);
    unsigned short* wq   = (unsigned short*)alloc((size_t)INNER*DIM*2);
    unsigned short* wkv  = (unsigned short*)alloc((size_t)2*INNER*DIM*2);
    unsigned short* wpr  = (unsigned short*)alloc((size_t)DIM*INNER*2);
    unsigned short* wf1  = (unsigned short*)alloc((size_t)HIDDEN*DIM*2);
    unsigned short* wf2  = (unsigned short*)alloc((size_t)DIM*HIDDEN*2);

    // 0) convert + permute all weights (one launch)
    cvt_all_kernel<<<dim3(320), 256, 0, stream>>>(
        q_w, wq, kv_w, wkv, proj_w, wpr, fc1_w, wf1, fc2_w, wf2);

    // 1) LayerNorms of x and y -> PA(128)
    ln_dual_kernel<<<dim3(ROWS/4, 2), 256, 0, stream>>>(
        x, norm_x_w, norm_x_b, xn, y, norm_y_w, norm_y_b, yn);

    // 2) q + kv projections in one launch (8B vectorized scatter stores)
    qkv_kernel<<<dim3(48, ROWS/64), 256, 0, stream>>>(xn, yn, wq, wkv, qb, kpm, vpm);

    // 3) attention -> ob in PA(1024); 512 blocks x 4 waves, 32x32 MFMA
    attn_kernel<<<dim3(512), 256, 0, stream>>>(qb, kpm, vpm, ob);

    // 4) proj + bias + ls1*resid + LN -> x1 (f32) and hin (PA 128)
    projln_kernel<<<dim3(ROWS/16), 256, 0, stream>>>(
        ob, wpr, proj_b, ls1_gamma, x, x1, norm_o_w, norm_o_b, hin);

    // 5) fc1 + relu + fc2 + bias + ls2*resid -> d_out (f32)
    fc_kernel<<<dim3(ROWS/16), 256, 0, stream>>>(
        hin, wf1, fc1_b, wf2, fc2_b, ls2_gamma, x1, (float*)d_out);
}

// Round 16
// 120.924 us; speedup vs baseline: 1.2300x; 1.2300x over previous
//
#include <hip/hip_runtime.h>
#include <stdint.h>

#define DIM    128
#define HEADS  8
#define INNER  1024
#define HIDDEN 512
#define BATCH  8
#define SEQ    1024
#define ROWS   8192   // BATCH*SEQ

typedef __attribute__((ext_vector_type(8))) short bf16x8;
typedef __attribute__((ext_vector_type(4))) float f32x4;
typedef __attribute__((ext_vector_type(16))) float f32x16;
typedef __attribute__((ext_vector_type(4))) unsigned short u16x4;

// q is pre-scaled by 1/sqrt(128) * log2(e) so attention works in exp2 domain
#define QSCALE (0.08838834764831845f * 1.4426950408889634f)

#define AS1 __attribute__((address_space(1)))
#define AS3 __attribute__((address_space(3)))

static __device__ __forceinline__ float b2f(unsigned short u) {
    union { float f; unsigned int i; } v; v.i = ((unsigned int)u) << 16; return v.f;
}
static __device__ __forceinline__ unsigned short f2b(float f) {
    union { float f; unsigned int i; } v; v.f = f;
    unsigned int x = v.i;
    return (unsigned short)((x + 0x7fffu + ((x >> 16) & 1u)) >> 16);
}
static __device__ __forceinline__ unsigned int cvt_pk_bf16(float a, float b) {
    unsigned int r;
    asm("v_cvt_pk_bf16_f32 %0, %1, %2" : "=v"(r) : "v"(a), "v"(b));
    return r;
}
// async global->LDS, 16B per lane; LDS dest is wave-uniform base + lane*16
static __device__ __forceinline__ void gl_lds16(const unsigned short* g, unsigned short* l) {
    __builtin_amdgcn_global_load_lds((AS1 void*)g, (AS3 void*)l, 16, 0, 0);
}

// MFMA A-fragment ("PA") layout: lane-linear 1KB blocks per (row-tile, k-chunk).
static __device__ __forceinline__ size_t pa_idx(int row, int k, int K) {
    return ((size_t)((row >> 4) * (K >> 5) + (k >> 5)) << 9)
         + (size_t)(((((k >> 3) & 3) << 4) + (row & 15)) << 3) + (size_t)(k & 7);
}

// ---------------- weight f32 -> bf16 + permute to PA layout ----------------
template<int K>
static __device__ __forceinline__ void cvtw(const float* __restrict__ W,
                                            unsigned short* __restrict__ Wp, int j)
{
    const int c  = j & 15;
    const int gw = (j >> 4) & 3;
    const int blk = j >> 6;
    const int ks = blk & ((K >> 5) - 1);
    const int nt = blk / (K >> 5);
    const int n  = nt * 16 + c;
    const int kb = ks * 32 + gw * 8;
    const float4 a = *(const float4*)(W + (size_t)n * K + kb);
    const float4 b = *(const float4*)(W + (size_t)n * K + kb + 4);
    u16x4 o0, o1;
    o0[0] = f2b(a.x); o0[1] = f2b(a.y); o0[2] = f2b(a.z); o0[3] = f2b(a.w);
    o1[0] = f2b(b.x); o1[1] = f2b(b.y); o1[2] = f2b(b.z); o1[3] = f2b(b.w);
    *(u16x4*)(Wp + (size_t)j * 8)     = o0;
    *(u16x4*)(Wp + (size_t)j * 8 + 4) = o1;
}

__global__ __launch_bounds__(256)
void cvt_all_kernel(const float* __restrict__ s0, unsigned short* __restrict__ d0,
                    const float* __restrict__ s1, unsigned short* __restrict__ d1,
                    const float* __restrict__ s2, unsigned short* __restrict__ d2,
                    const float* __restrict__ s3, unsigned short* __restrict__ d3,
                    const float* __restrict__ s4, unsigned short* __restrict__ d4)
{
    int j = blockIdx.x * 256 + threadIdx.x;
    if (j < 16384)                 { cvtw<128>(s0, d0, j);  return; }
    if ((j -= 16384) < 32768)      { cvtw<128>(s1, d1, j);  return; }
    if ((j -= 32768) < 16384)      { cvtw<1024>(s2, d2, j); return; }
    if ((j -= 16384) < 8192)       { cvtw<128>(s3, d3, j);  return; }
    j -= 8192;                       cvtw<512>(s4, d4, j);
}

// ---------------- LayerNorm (x and y): f32 row-major in, bf16 PA(128) out ----------------
static __device__ __forceinline__ void ln_row(const float* __restrict__ in,
                                              const float* __restrict__ w,
                                              const float* __restrict__ b,
                                              unsigned short* __restrict__ out,
                                              int row, int lane)
{
    const float2 xv = *(const float2*)(in + (size_t)row*DIM + lane*2);
    float x0 = xv.x, x1 = xv.y;
    float s = x0 + x1;
    float q = x0*x0 + x1*x1;
    #pragma unroll
    for (int off = 32; off > 0; off >>= 1) {
        s += __shfl_xor(s, off);
        q += __shfl_xor(q, off);
    }
    const float mu  = s * (1.0f/128.0f);
    const float var = q * (1.0f/128.0f) - mu*mu;
    const float rs  = rsqrtf(var + 1e-5f);
    const float2 wv = *(const float2*)(w + lane*2);
    const float2 bv = *(const float2*)(b + lane*2);
    unsigned short o0 = f2b((x0 - mu) * rs * wv.x + bv.x);
    unsigned short o1 = f2b((x1 - mu) * rs * wv.y + bv.y);
    *(unsigned int*)(out + pa_idx(row, lane*2, 128)) = (unsigned int)o0 | ((unsigned int)o1 << 16);
}

__global__ __launch_bounds__(256)
void ln_dual_kernel(const float* __restrict__ inx, const float* __restrict__ wx,
                    const float* __restrict__ bx, unsigned short* __restrict__ outx,
                    const float* __restrict__ iny, const float* __restrict__ wy,
                    const float* __restrict__ by, unsigned short* __restrict__ outy)
{
    const int row  = blockIdx.x * 4 + (threadIdx.x >> 6);
    const int lane = threadIdx.x & 63;
    if (blockIdx.y == 0) ln_row(inx, wx, bx, outx, row, lane);
    else                 ln_row(iny, wy, by, outy, row, lane);
}

// ---------------- merged q + kv projection GEMM (one launch, vectorized stores) ----------------
// blockIdx.x: 0..15 -> q (swapped operands), 16..31 -> K (swapped), 32..47 -> V (normal)
// K layout per bh,chunk(32m): elem = chunk*4096 + (d>>4)*512 + ((d>>3)&1)*256 + (m&31)*8 + (d&7)
// V layout per bh,chunk(32m): elem = chunk*4096 + ((p>>5)*2 + ((m>>4)&1))*512 + ((m>>3)&1)*256 + (p&31)*8 + (m&7)
__global__ __launch_bounds__(256)
void qkv_kernel(const unsigned short* __restrict__ xn,  // PA(128)
                const unsigned short* __restrict__ yn,  // PA(128)
                const unsigned short* __restrict__ wq,  // PA(128), 1024 rows
                const unsigned short* __restrict__ wkv, // PA(128), 2048 rows
                unsigned short* __restrict__ qb,
                unsigned short* __restrict__ kpm,
                unsigned short* __restrict__ vpm)
{
    const int lane = threadIdx.x & 63;
    const int wave = threadIdx.x >> 6;
    const int g    = lane >> 4;
    const int c16  = lane & 15;
    const int bx   = blockIdx.x;
    const int by   = blockIdx.y;

    f32x4 acc[4];
    #pragma unroll
    for (int t = 0; t < 4; ++t) acc[t] = (f32x4){0.f, 0.f, 0.f, 0.f};

    if (bx < 32) {
        // ---- swapped: A = weight tile (rows of D), B = activation tile (cols of D) ----
        const bool isq = bx < 16;
        const unsigned short* W = isq ? wq : wkv;
        const unsigned short* Aact = isq ? xn : yn;
        const int wt = (bx & 15) * 4 + wave;           // weight tile (16 rows each)
        #pragma unroll
        for (int ks = 0; ks < 4; ++ks) {
            bf16x8 wf = *(const bf16x8*)(W + (((size_t)(wt*4 + ks)) << 9) + lane*8);
            #pragma unroll
            for (int t = 0; t < 4; ++t) {
                bf16x8 af = *(const bf16x8*)(Aact + (((size_t)((by*4 + t)*4 + ks)) << 9) + lane*8);
                acc[t] = __builtin_amdgcn_mfma_f32_16x16x32_bf16(wf, af, acc[t], 0, 0, 0);
            }
        }
        const int n_w0 = (bx & 15)*64 + wave*16 + g*4;  // weight row (p/d dim), r walks +1
        const int hh = n_w0 >> 7;
        const int p0 = n_w0 & 127;
        #pragma unroll
        for (int t = 0; t < 4; ++t) {
            const int m_row = by*64 + t*16 + c16;
            const int bb = m_row >> 10, m = m_row & 1023;
            u16x4 o;
            if (isq) {
                o[0] = f2b(acc[t][0]*QSCALE); o[1] = f2b(acc[t][1]*QSCALE);
                o[2] = f2b(acc[t][2]*QSCALE); o[3] = f2b(acc[t][3]*QSCALE);
                *(u16x4*)&qb[(((size_t)(bb*HEADS + hh))*SEQ + m)*DIM + p0] = o;
            } else {
                o[0] = f2b(acc[t][0]); o[1] = f2b(acc[t][1]);
                o[2] = f2b(acc[t][2]); o[3] = f2b(acc[t][3]);
                const int chunk = m >> 5;
                const int ds = p0 >> 4, dhi = (p0 >> 3) & 1, de = p0 & 7;
                *(u16x4*)&kpm[(size_t)(bb*HEADS + hh)*SEQ*DIM
                    + (size_t)(chunk*4096 + ds*512 + dhi*256 + (m & 31)*8 + de)] = o;
            }
        }
    } else {
        // ---- normal: V half (weight rows 1024..2047 of wkv) ----
        const int mt = by*4 + wave;
        #pragma unroll
        for (int ks = 0; ks < 4; ++ks) {
            bf16x8 af = *(const bf16x8*)(yn + (((size_t)(mt*4 + ks)) << 9) + lane*8);
            #pragma unroll
            for (int t = 0; t < 4; ++t) {
                const int nt = 64 + (bx - 32)*4 + t;
                bf16x8 wf = *(const bf16x8*)(wkv + (((size_t)(nt*4 + ks)) << 9) + lane*8);
                acc[t] = __builtin_amdgcn_mfma_f32_16x16x32_bf16(af, wf, acc[t], 0, 0, 0);
            }
        }
        const int m_row0 = by*64 + wave*16 + g*4;       // seq row, r walks +1
        const int bb = m_row0 >> 10;
        const int m0 = m_row0 & 1023;
        const int chunk = m0 >> 5, s = (m0 >> 4) & 1, mhi = (m0 >> 3) & 1, e0 = m0 & 7;
        #pragma unroll
        for (int t = 0; t < 4; ++t) {
            const int p = (bx - 32)*64 + t*16 + c16;
            const int hh = p >> 7, pp = p & 127, pt = pp >> 5, pc = pp & 31;
            u16x4 o;
            o[0] = f2b(acc[t][0]); o[1] = f2b(acc[t][1]);
            o[2] = f2b(acc[t][2]); o[3] = f2b(acc[t][3]);
            *(u16x4*)&vpm[(size_t)(bb*HEADS + hh)*SEQ*DIM
                + (size_t)(chunk*4096 + (pt*2 + s)*512 + mhi*256 + pc*8 + e0)] = o;
        }
    }
}

// ---------------- Flash attention v10: 8 waves, 32x32 MFMA, m-parity split + LDS merge ----------------
// waves 0-3 (group 0): even chunks; waves 4-7 (group 1): odd chunks. Same 128 q-rows.
// 16 iterations; per iter stage 2 chunks (32KB) double-buffered; merge partials at end via LDS.
__global__ __launch_bounds__(512, 4)
void attn_kernel(const unsigned short* __restrict__ qbuf,  // (B,H,N,P) pre-scaled
                 const unsigned short* __restrict__ kperm, // per bh: [chunk][4096] (A-frag linear)
                 const unsigned short* __restrict__ vperm, // per bh: [chunk][4096] (B-frag linear)
                 unsigned short* __restrict__ obuf)        // PA(1024) over rows (B*SEQ)
{
    __shared__ unsigned short kvbuf[2][2][8192];  // [k/v][buf][parity*4096 + ...] = 64KB
    __shared__ float limibuf[2][4][64];           // [li/mi][wsub][lane]

    const int lane = threadIdx.x & 63;
    const int wave = threadIdx.x >> 6;         // 0..7
    const int wsub = wave & 3;
    const int gsel = wave >> 2;                // chunk parity this wave-group owns
    const int l31  = lane & 31;
    const int hi   = lane >> 5;

    // XCD swizzle: all 8 q-blocks of one bh land on the same XCD (j%8)
    const int j    = blockIdx.x;
    const int bh   = (j & 7) * 8 + (j >> 6);
    const int nblk = (j >> 3) & 7;
    const int n0   = nblk * 128 + wsub * 32;
    const int bb   = bh >> 3, hh = bh & 7;

    const unsigned short* Q  = qbuf  + (size_t)bh * SEQ * DIM;
    const unsigned short* Kb = kperm + (size_t)bh * SEQ * DIM;
    const unsigned short* Vb = vperm + (size_t)bh * SEQ * DIM;

    // stage chunks 0,1 into buf 0: wave w covers segs {2w, 2w+1} of the 16KB (K) and (V)
    #pragma unroll
    for (int i = 0; i < 2; ++i) {
        const int s = wave*2 + i;
        gl_lds16(Kb + s*512 + lane*8, &kvbuf[0][0][s*512]);
        gl_lds16(Vb + s*512 + lane*8, &kvbuf[1][0][s*512]);
    }

    // Q B-fragments: lane holds Q[q=n0+l31][d = ds*16 + hi*8 + e]
    bf16x8 qf[8];
    #pragma unroll
    for (int ds = 0; ds < 8; ++ds)
        qf[ds] = *(const bf16x8*)(Q + (size_t)(n0 + l31)*DIM + ds*16 + hi*8);

    f32x16 oacc[4];
    #pragma unroll
    for (int pt = 0; pt < 4; ++pt)
        #pragma unroll
        for (int r = 0; r < 16; ++r) oacc[pt][r] = 0.f;
    float mi = 8.0f;      // row-uniform initial max guess (exp2 domain)
    float li = 0.f;       // per-lane partial (q = l31, this lane's m-half, this group's chunks)

    const int po = gsel * 4096;   // parity offset inside a buffer

    __syncthreads();   // chunks 0,1 staged

    int cur = 0;
    for (int ip = 0; ip < 16; ++ip, cur ^= 1) {
        // ---- stage chunks 2ip+2, 2ip+3 into buf[cur^1] ----
        if (ip != 15) {
            const unsigned short* Ks = Kb + (size_t)(2*ip + 2) * 4096;
            const unsigned short* Vs = Vb + (size_t)(2*ip + 2) * 4096;
            #pragma unroll
            for (int i = 0; i < 2; ++i) {
                const int s = wave*2 + i;
                gl_lds16(Ks + s*512 + lane*8, &kvbuf[0][cur ^ 1][s*512]);
                gl_lds16(Vs + s*512 + lane*8, &kvbuf[1][cur ^ 1][s*512]);
            }
        }

        // ---- QK^T on this group's chunk: S^T[m][q], 8 MFMAs over d ----
        f32x16 st;
        #pragma unroll
        for (int r = 0; r < 16; ++r) st[r] = 0.f;
        #pragma unroll
        for (int ds = 0; ds < 8; ++ds) {
            bf16x8 kf = *(const bf16x8*)&kvbuf[0][cur][po + ds*512 + lane*8];
            st = __builtin_amdgcn_mfma_f32_32x32x16_bf16(kf, qf[ds], st, 0, 0, 0);
        }

        // ---- softmax, per-lane common path (q = l31) ----
        float cmax = st[0];
        #pragma unroll
        for (int r = 1; r < 16; ++r) cmax = fmaxf(cmax, st[r]);

        if (!__all(cmax - mi <= 8.0f)) {   // rare rescale path
            float rmax = fmaxf(cmax, __shfl_xor(cmax, 32));
            const float mnew  = fmaxf(mi, rmax);
            const float alpha = exp2f(mi - mnew);
            mi = mnew;
            li *= alpha;
            float ar[16];
            #pragma unroll
            for (int r = 0; r < 16; ++r)
                ar[r] = __shfl(alpha, (r & 3) + 8*(r >> 2) + 4*hi);
            #pragma unroll
            for (int pt = 0; pt < 4; ++pt)
                #pragma unroll
                for (int r = 0; r < 16; ++r) oacc[pt][r] *= ar[r];
        }

        // p in place of st
        #pragma unroll
        for (int r = 0; r < 16; ++r) st[r] = exp2f(st[r] - mi);
        li += (((st[0]+st[1]) + (st[2]+st[3])) + ((st[4]+st[5]) + (st[6]+st[7])))
            + (((st[8]+st[9]) + (st[10]+st[11])) + ((st[12]+st[13]) + (st[14]+st[15])));

        // ---- P -> A-fragments in-register (cvt_pk + shfl_xor32 + select) ----
        union { unsigned w[4]; bf16x8 v; } pa0, pa1;
        {
            unsigned a0 = cvt_pk_bf16(st[0], st[1]),  a1 = cvt_pk_bf16(st[2], st[3]);
            unsigned b0 = cvt_pk_bf16(st[4], st[5]),  b1 = cvt_pk_bf16(st[6], st[7]);
            unsigned sa0 = __shfl_xor((int)a0, 32), sb0 = __shfl_xor((int)b0, 32);
            unsigned sa1 = __shfl_xor((int)a1, 32), sb1 = __shfl_xor((int)b1, 32);
            pa0.w[0] = hi ? sb0 : a0;
            pa0.w[1] = hi ? sb1 : a1;
            pa0.w[2] = hi ? b0  : sa0;
            pa0.w[3] = hi ? b1  : sa1;
        }
        {
            unsigned a0 = cvt_pk_bf16(st[8], st[9]),   a1 = cvt_pk_bf16(st[10], st[11]);
            unsigned b0 = cvt_pk_bf16(st[12], st[13]), b1 = cvt_pk_bf16(st[14], st[15]);
            unsigned sa0 = __shfl_xor((int)a0, 32), sb0 = __shfl_xor((int)b0, 32);
            unsigned sa1 = __shfl_xor((int)a1, 32), sb1 = __shfl_xor((int)b1, 32);
            pa1.w[0] = hi ? sb0 : a0;
            pa1.w[1] = hi ? sb1 : a1;
            pa1.w[2] = hi ? b0  : sa0;
            pa1.w[3] = hi ? b1  : sa1;
        }

        // ---- PV: oacc[pt] += P(s) x V(pt,s); vf loaded lazily per pt ----
        #pragma unroll
        for (int pt = 0; pt < 4; ++pt) {
            bf16x8 vf0 = *(const bf16x8*)&kvbuf[1][cur][po + (pt*2 + 0)*512 + lane*8];
            bf16x8 vf1 = *(const bf16x8*)&kvbuf[1][cur][po + (pt*2 + 1)*512 + lane*8];
            oacc[pt] = __builtin_amdgcn_mfma_f32_32x32x16_bf16(pa0.v, vf0, oacc[pt], 0, 0, 0);
            oacc[pt] = __builtin_amdgcn_mfma_f32_32x32x16_bf16(pa1.v, vf1, oacc[pt], 0, 0, 0);
        }

        __syncthreads();   // stage(next) drained + all waves done with buf[cur]
    }

    // ---- merge group 1 -> group 0 via LDS (kvbuf is dead; exact 64KB fit) ----
    float* xch = (float*)&kvbuf[0][0][0];
    if (gsel == 1) {
        #pragma unroll
        for (int pt = 0; pt < 4; ++pt)
            #pragma unroll
            for (int v = 0; v < 4; ++v) {
                const int vi = pt*4 + v;
                f32x4 w4 = { oacc[pt][v*4+0], oacc[pt][v*4+1], oacc[pt][v*4+2], oacc[pt][v*4+3] };
                *(f32x4*)&xch[(size_t)(wsub*64 + lane)*64 + ((vi ^ (lane & 15)) << 2)] = w4;
            }
        limibuf[0][wsub][lane] = li;
        limibuf[1][wsub][lane] = mi;
    }
    __syncthreads();
    if (gsel == 0) {
        const float li_b = limibuf[0][wsub][lane];
        const float mi_b = limibuf[1][wsub][lane];
        const float M  = fmaxf(mi, mi_b);
        const float fa = exp2f(mi - M);
        const float fb = exp2f(mi_b - M);
        float lim = li*fa + li_b*fb;
        lim += __shfl_xor(lim, 32);
        const float inv = 1.f / lim;

        float FA[16], FB[16], LR[16];
        #pragma unroll
        for (int r = 0; r < 16; ++r) {
            const int qs = (r & 3) + 8*(r >> 2) + 4*hi;
            FA[r] = __shfl(fa, qs);
            FB[r] = __shfl(fb, qs);
            LR[r] = __shfl(inv, qs);
        }

        #pragma unroll
        for (int pt = 0; pt < 4; ++pt) {
            f32x4 ob[4];
            #pragma unroll
            for (int v = 0; v < 4; ++v) {
                const int vi = pt*4 + v;
                ob[v] = *(const f32x4*)&xch[(size_t)(wsub*64 + lane)*64 + ((vi ^ (lane & 15)) << 2)];
            }
            #pragma unroll
            for (int r = 0; r < 16; ++r) {
                const float om = oacc[pt][r]*FA[r] + ob[r >> 2][r & 3]*FB[r];
                const int qr  = (r & 3) + 8*(r >> 2) + 4*hi;
                const int row = bb*SEQ + n0 + qr;
                const int k   = hh*DIM + pt*32 + l31;
                obuf[pa_idx(row, k, INNER)] = f2b(om * LR[r]);
            }
        }
    }
}

// ---------------- proj GEMM + bias + ls1*resid + LayerNorm fused ----------------
__global__ __launch_bounds__(256)
void projln_kernel(const unsigned short* __restrict__ A,   // ob PA(1024)
                   const unsigned short* __restrict__ W,   // wpr PA(1024), 128 rows
                   const float* __restrict__ bias,         // proj_b
                   const float* __restrict__ gamma,        // ls1_gamma
                   const float* __restrict__ xres,         // x (f32)
                   float* __restrict__ x1,                 // out: residual (f32)
                   const float* __restrict__ lnw, const float* __restrict__ lnb,
                   unsigned short* __restrict__ hin)       // out: PA(128)
{
    __shared__ float part[4][16][2];

    const int lane = threadIdx.x & 63;
    const int wave = threadIdx.x >> 6;
    const int g    = lane >> 4;
    const int c16  = lane & 15;
    const int mt   = blockIdx.x;

    f32x4 acc[2];
    acc[0] = (f32x4){0.f,0.f,0.f,0.f};
    acc[1] = (f32x4){0.f,0.f,0.f,0.f};

    #pragma unroll 4
    for (int ks = 0; ks < 32; ++ks) {
        bf16x8 af = *(const bf16x8*)(A + (((size_t)(mt*32 + ks)) << 9) + lane*8);
        #pragma unroll
        for (int t = 0; t < 2; ++t) {
            bf16x8 wf = *(const bf16x8*)(W + (((size_t)((wave*2 + t)*32 + ks)) << 9) + lane*8);
            acc[t] = __builtin_amdgcn_mfma_f32_16x16x32_bf16(af, wf, acc[t], 0, 0, 0);
        }
    }

    float v[2][4];
    #pragma unroll
    for (int t = 0; t < 2; ++t) {
        const int col = wave*32 + t*16 + c16;
        const float bb = bias[col], gg = gamma[col];
        #pragma unroll
        for (int r = 0; r < 4; ++r) {
            const int row = mt*16 + g*4 + r;
            const float xv = xres[(size_t)row*DIM + col];
            v[t][r] = xv + (acc[t][r] + bb) * gg;
            x1[(size_t)row*DIM + col] = v[t][r];
        }
    }
    #pragma unroll
    for (int r = 0; r < 4; ++r) {
        float s = v[0][r] + v[1][r];
        float q = v[0][r]*v[0][r] + v[1][r]*v[1][r];
        #pragma unroll
        for (int off = 1; off < 16; off <<= 1) {
            s += __shfl_xor(s, off);
            q += __shfl_xor(q, off);
        }
        if (c16 == 0) { part[wave][g*4+r][0] = s; part[wave][g*4+r][1] = q; }
    }
    __syncthreads();

    #pragma unroll
    for (int r = 0; r < 4; ++r) {
        const int lr = g*4 + r;
        const float s = part[0][lr][0] + part[1][lr][0] + part[2][lr][0] + part[3][lr][0];
        const float q = part[0][lr][1] + part[1][lr][1] + part[2][lr][1] + part[3][lr][1];
        const float mu  = s * (1.0f/128.0f);
        const float var = q * (1.0f/128.0f) - mu*mu;
        const float rs  = rsqrtf(var + 1e-5f);
        const int row = mt*16 + lr;
        #pragma unroll
        for (int t = 0; t < 2; ++t) {
            const int col = wave*32 + t*16 + c16;
            const float hv = (v[t][r] - mu) * rs * lnw[col] + lnb[col];
            hin[pa_idx(row, col, 128)] = f2b(hv);
        }
    }
}

// ---------------- fc1 + relu + fc2 + bias + ls2*resid fused ----------------
__global__ __launch_bounds__(256)
void fc_kernel(const unsigned short* __restrict__ hin,  // PA(128)
               const unsigned short* __restrict__ W1,   // PA(128), 512 rows
               const float* __restrict__ b1,
               const unsigned short* __restrict__ W2,   // PA(512), 128 rows
               const float* __restrict__ b2,
               const float* __restrict__ gamma2,        // ls2
               const float* __restrict__ x1,            // f32 residual
               float* __restrict__ dout)
{
    __shared__ unsigned short h[16][520];   // 512 + 8 pad

    const int lane = threadIdx.x & 63;
    const int wave = threadIdx.x >> 6;
    const int g    = lane >> 4;
    const int c16  = lane & 15;
    const int mt   = blockIdx.x;

    f32x4 a1[8];
    #pragma unroll
    for (int t = 0; t < 8; ++t) a1[t] = (f32x4){0.f,0.f,0.f,0.f};
    #pragma unroll
    for (int ks = 0; ks < 4; ++ks) {
        bf16x8 af = *(const bf16x8*)(hin + (((size_t)(mt*4 + ks)) << 9) + lane*8);
        #pragma unroll
        for (int t = 0; t < 8; ++t) {
            const int nt = wave*8 + t;
            bf16x8 wf = *(const bf16x8*)(W1 + (((size_t)(nt*4 + ks)) << 9) + lane*8);
            a1[t] = __builtin_amdgcn_mfma_f32_16x16x32_bf16(af, wf, a1[t], 0, 0, 0);
        }
    }
    #pragma unroll
    for (int t = 0; t < 8; ++t) {
        const int col = wave*128 + t*16 + c16;
        const float bb = b1[col];
        #pragma unroll
        for (int r = 0; r < 4; ++r)
            h[g*4 + r][col] = f2b(fmaxf(a1[t][r] + bb, 0.f));
    }
    __syncthreads();

    f32x4 a2[2];
    a2[0] = (f32x4){0.f,0.f,0.f,0.f};
    a2[1] = (f32x4){0.f,0.f,0.f,0.f};
    #pragma unroll 4
    for (int ks = 0; ks < 16; ++ks) {
        bf16x8 af = *(const bf16x8*)&h[c16][ks*32 + g*8];
        #pragma unroll
        for (int t = 0; t < 2; ++t) {
            const int nt = wave*2 + t;
            bf16x8 wf = *(const bf16x8*)(W2 + (((size_t)(nt*16 + ks)) << 9) + lane*8);
            a2[t] = __builtin_amdgcn_mfma_f32_16x16x32_bf16(af, wf, a2[t], 0, 0, 0);
        }
    }
    #pragma unroll
    for (int t = 0; t < 2; ++t) {
        const int col = wave*32 + t*16 + c16;
        const float bb = b2[col], gg = gamma2[col];
        #pragma unroll
        for (int r = 0; r < 4; ++r) {
            const int row = mt*16 + g*4 + r;
            dout[(size_t)row*DIM + col] = x1[(size_t)row*DIM + col] + (a2[t][r] + bb) * gg;
        }
    }
}

// ---------------- launch ----------------
extern "C" void kernel_launch(void* const* d_in, const int* in_sizes, int n_in,
                              void* d_out, int out_size, void* d_ws, size_t ws_size,
                              hipStream_t stream)
{
    const float* x         = (const float*)d_in[0];
    const float* y         = (const float*)d_in[1];
    const float* norm_x_w  = (const float*)d_in[2];
    const float* norm_x_b  = (const float*)d_in[3];
    const float* norm_y_w  = (const float*)d_in[4];
    const float* norm_y_b  = (const float*)d_in[5];
    const float* q_w       = (const float*)d_in[6];
    const float* kv_w      = (const float*)d_in[7];
    const float* proj_w    = (const float*)d_in[8];
    const float* proj_b    = (const float*)d_in[9];
    const float* ls1_gamma = (const float*)d_in[10];
    const float* norm_o_w  = (const float*)d_in[11];
    const float* norm_o_b  = (const float*)d_in[12];
    const float* fc1_w     = (const float*)d_in[13];
    const float* fc1_b     = (const float*)d_in[14];
    const float* fc2_w     = (const float*)d_in[15];
    const float* fc2_b     = (const float*)d_in[16];
    const float* ls2_gamma = (const float*)d_in[17];

    char* ws = (char*)d_ws;
    size_t off = 0;
    auto alloc = [&](size_t bytes) {
        void* p = ws + off;
        off += (bytes + 255) & ~(size_t)255;
        return p;
    };
    unsigned short* xn  = (unsigned short*)alloc((size_t)ROWS*DIM*2);
    unsigned short* yn  = (unsigned short*)alloc((size_t)ROWS*DIM*2);
    unsigned short* qb  = (unsigned short*)alloc((size_t)ROWS*INNER*2);
    unsigned short* kpm = (unsigned short*)alloc((size_t)ROWS*INNER*2);
    unsigned short* vpm = (unsigned short*)alloc((size_t)ROWS*INNER*2);
    unsigned short* ob  = (unsigned short*)alloc((size_t)ROWS*INNER*2);
    float*          x1  = (float*)alloc((size_t)ROWS*DIM*4);
    unsigned short* hin = (unsigned short*)alloc((size_t)ROWS*DIM*2);
    unsigned short* wq   = (unsigned short*)alloc((size_t)INNER*DIM*2);
    unsigned short* wkv  = (unsigned short*)alloc((size_t)2*INNER*DIM*2);
    unsigned short* wpr  = (unsigned short*)alloc((size_t)DIM*INNER*2);
    unsigned short* wf1  = (unsigned short*)alloc((size_t)HIDDEN*DIM*2);
    unsigned short* wf2  = (unsigned short*)alloc((size_t)DIM*HIDDEN*2);

    // 0) convert + permute all weights (one launch)
    cvt_all_kernel<<<dim3(320), 256, 0, stream>>>(
        q_w, wq, kv_w, wkv, proj_w, wpr, fc1_w, wf1, fc2_w, wf2);

    // 1) LayerNorms of x and y -> PA(128)
    ln_dual_kernel<<<dim3(ROWS/4, 2), 256, 0, stream>>>(
        x, norm_x_w, norm_x_b, xn, y, norm_y_w, norm_y_b, yn);

    // 2) q + kv projections in one launch (8B vectorized scatter stores)
    qkv_kernel<<<dim3(48, ROWS/64), 256, 0, stream>>>(xn, yn, wq, wkv, qb, kpm, vpm);

    // 3) attention -> ob in PA(1024); 512 blocks x 8 waves, 32x32 MFMA, m-parity split
    attn_kernel<<<dim3(512), 512, 0, stream>>>(qb, kpm, vpm, ob);

    // 4) proj + bias + ls1*resid + LN -> x1 (f32) and hin (PA 128)
    projln_kernel<<<dim3(ROWS/16), 256, 0, stream>>>(
        ob, wpr, proj_b, ls1_gamma, x, x1, norm_o_w, norm_o_b, hin);

    // 5) fc1 + relu + fc2 + bias + ls2*resid -> d_out (f32)
    fc_kernel<<<dim3(ROWS/16), 256, 0, stream>>>(
        hin, wf1, fc1_b, wf2, fc2_b, ls2_gamma, x1, (float*)d_out);
}

// Round 17
// 110.176 us; speedup vs baseline: 1.3500x; 1.0976x over previous
//
#include <hip/hip_runtime.h>
#include <stdint.h>

#define DIM    128
#define HEADS  8
#define INNER  1024
#define HIDDEN 512
#define BATCH  8
#define SEQ    1024
#define ROWS   8192   // BATCH*SEQ

typedef __attribute__((ext_vector_type(8))) short bf16x8;
typedef __attribute__((ext_vector_type(4))) float f32x4;
typedef __attribute__((ext_vector_type(4))) unsigned short u16x4;

// q is pre-scaled by 1/sqrt(128) * log2(e) so attention works in exp2 domain
#define QSCALE (0.08838834764831845f * 1.4426950408889634f)

#define AS1 __attribute__((address_space(1)))
#define AS3 __attribute__((address_space(3)))

static __device__ __forceinline__ float b2f(unsigned short u) {
    union { float f; unsigned int i; } v; v.i = ((unsigned int)u) << 16; return v.f;
}
static __device__ __forceinline__ unsigned short f2b(float f) {
    union { float f; unsigned int i; } v; v.f = f;
    unsigned int x = v.i;
    return (unsigned short)((x + 0x7fffu + ((x >> 16) & 1u)) >> 16);
}
static __device__ __forceinline__ unsigned int cvt_pk_bf16(float a, float b) {
    unsigned int r;
    asm("v_cvt_pk_bf16_f32 %0, %1, %2" : "=v"(r) : "v"(a), "v"(b));
    return r;
}
// async global->LDS, 16B per lane; LDS dest is wave-uniform base + lane*16
static __device__ __forceinline__ void gl_lds16(const unsigned short* g, unsigned short* l) {
    __builtin_amdgcn_global_load_lds((AS1 void*)g, (AS3 void*)l, 16, 0, 0);
}

// MFMA A-fragment ("PA") layout: lane-linear 1KB blocks per (row-tile, k-chunk).
static __device__ __forceinline__ size_t pa_idx(int row, int k, int K) {
    return ((size_t)((row >> 4) * (K >> 5) + (k >> 5)) << 9)
         + (size_t)(((((k >> 3) & 3) << 4) + (row & 15)) << 3) + (size_t)(k & 7);
}

// ---------------- weight f32 -> bf16 + permute to PA layout ----------------
template<int K>
static __device__ __forceinline__ void cvtw(const float* __restrict__ W,
                                            unsigned short* __restrict__ Wp, int j)
{
    const int c  = j & 15;
    const int gw = (j >> 4) & 3;
    const int blk = j >> 6;
    const int ks = blk & ((K >> 5) - 1);
    const int nt = blk / (K >> 5);
    const int n  = nt * 16 + c;
    const int kb = ks * 32 + gw * 8;
    const float4 a = *(const float4*)(W + (size_t)n * K + kb);
    const float4 b = *(const float4*)(W + (size_t)n * K + kb + 4);
    u16x4 o0, o1;
    o0[0] = f2b(a.x); o0[1] = f2b(a.y); o0[2] = f2b(a.z); o0[3] = f2b(a.w);
    o1[0] = f2b(b.x); o1[1] = f2b(b.y); o1[2] = f2b(b.z); o1[3] = f2b(b.w);
    *(u16x4*)(Wp + (size_t)j * 8)     = o0;
    *(u16x4*)(Wp + (size_t)j * 8 + 4) = o1;
}

__global__ __launch_bounds__(256)
void cvt_all_kernel(const float* __restrict__ s0, unsigned short* __restrict__ d0,
                    const float* __restrict__ s1, unsigned short* __restrict__ d1,
                    const float* __restrict__ s2, unsigned short* __restrict__ d2,
                    const float* __restrict__ s3, unsigned short* __restrict__ d3,
                    const float* __restrict__ s4, unsigned short* __restrict__ d4)
{
    int j = blockIdx.x * 256 + threadIdx.x;
    if (j < 16384)                 { cvtw<128>(s0, d0, j);  return; }
    if ((j -= 16384) < 32768)      { cvtw<128>(s1, d1, j);  return; }
    if ((j -= 32768) < 16384)      { cvtw<1024>(s2, d2, j); return; }
    if ((j -= 16384) < 8192)       { cvtw<128>(s3, d3, j);  return; }
    j -= 8192;                       cvtw<512>(s4, d4, j);
}

// ---------------- LayerNorm (x and y): f32 row-major in, bf16 PA(128) out ----------------
static __device__ __forceinline__ void ln_row(const float* __restrict__ in,
                                              const float* __restrict__ w,
                                              const float* __restrict__ b,
                                              unsigned short* __restrict__ out,
                                              int row, int lane)
{
    const float2 xv = *(const float2*)(in + (size_t)row*DIM + lane*2);
    float x0 = xv.x, x1 = xv.y;
    float s = x0 + x1;
    float q = x0*x0 + x1*x1;
    #pragma unroll
    for (int off = 32; off > 0; off >>= 1) {
        s += __shfl_xor(s, off);
        q += __shfl_xor(q, off);
    }
    const float mu  = s * (1.0f/128.0f);
    const float var = q * (1.0f/128.0f) - mu*mu;
    const float rs  = rsqrtf(var + 1e-5f);
    const float2 wv = *(const float2*)(w + lane*2);
    const float2 bv = *(const float2*)(b + lane*2);
    unsigned short o0 = f2b((x0 - mu) * rs * wv.x + bv.x);
    unsigned short o1 = f2b((x1 - mu) * rs * wv.y + bv.y);
    *(unsigned int*)(out + pa_idx(row, lane*2, 128)) = (unsigned int)o0 | ((unsigned int)o1 << 16);
}

__global__ __launch_bounds__(256)
void ln_dual_kernel(const float* __restrict__ inx, const float* __restrict__ wx,
                    const float* __restrict__ bx, unsigned short* __restrict__ outx,
                    const float* __restrict__ iny, const float* __restrict__ wy,
                    const float* __restrict__ by, unsigned short* __restrict__ outy)
{
    const int row  = blockIdx.x * 4 + (threadIdx.x >> 6);
    const int lane = threadIdx.x & 63;
    if (blockIdx.y == 0) ln_row(inx, wx, bx, outx, row, lane);
    else                 ln_row(iny, wy, by, outy, row, lane);
}

// ---------------- merged q + kv projection GEMM (one launch, vectorized stores) ----------------
// blockIdx.x: 0..15 -> q (swapped operands), 16..31 -> K (swapped), 32..47 -> V (normal)
// K permuted per bh: [chunk][s:2][ks:4][g:4][c16:16][e:8]  (lane-linear)
// V permuted per bh: [chunk][pc:8][g:4][c16:16][e:8]       (lane-linear)
__global__ __launch_bounds__(256)
void qkv_kernel(const unsigned short* __restrict__ xn,  // PA(128)
                const unsigned short* __restrict__ yn,  // PA(128)
                const unsigned short* __restrict__ wq,  // PA(128), 1024 rows
                const unsigned short* __restrict__ wkv, // PA(128), 2048 rows
                unsigned short* __restrict__ qb,
                unsigned short* __restrict__ kpm,
                unsigned short* __restrict__ vpm)
{
    const int lane = threadIdx.x & 63;
    const int wave = threadIdx.x >> 6;
    const int g    = lane >> 4;
    const int c16  = lane & 15;
    const int bx   = blockIdx.x;
    const int by   = blockIdx.y;

    f32x4 acc[4];
    #pragma unroll
    for (int t = 0; t < 4; ++t) acc[t] = (f32x4){0.f, 0.f, 0.f, 0.f};

    if (bx < 32) {
        // ---- swapped: A = weight tile (rows of D), B = activation tile (cols of D) ----
        const bool isq = bx < 16;
        const unsigned short* W = isq ? wq : wkv;
        const unsigned short* Aact = isq ? xn : yn;
        const int wt = (bx & 15) * 4 + wave;           // weight tile (16 rows each)
        #pragma unroll
        for (int ks = 0; ks < 4; ++ks) {
            bf16x8 wf = *(const bf16x8*)(W + (((size_t)(wt*4 + ks)) << 9) + lane*8);
            #pragma unroll
            for (int t = 0; t < 4; ++t) {
                bf16x8 af = *(const bf16x8*)(Aact + (((size_t)((by*4 + t)*4 + ks)) << 9) + lane*8);
                acc[t] = __builtin_amdgcn_mfma_f32_16x16x32_bf16(wf, af, acc[t], 0, 0, 0);
            }
        }
        const int n_w0 = (bx & 15)*64 + wave*16 + g*4;  // weight row (p-dim), r walks +1
        const int hh = n_w0 >> 7;
        const int p0 = n_w0 & 127;
        #pragma unroll
        for (int t = 0; t < 4; ++t) {
            const int m_row = by*64 + t*16 + c16;
            const int bb = m_row >> 10, m = m_row & 1023;
            u16x4 o;
            if (isq) {
                o[0] = f2b(acc[t][0]*QSCALE); o[1] = f2b(acc[t][1]*QSCALE);
                o[2] = f2b(acc[t][2]*QSCALE); o[3] = f2b(acc[t][3]*QSCALE);
                *(u16x4*)&qb[(((size_t)(bb*HEADS + hh))*SEQ + m)*DIM + p0] = o;
            } else {
                o[0] = f2b(acc[t][0]); o[1] = f2b(acc[t][1]);
                o[2] = f2b(acc[t][2]); o[3] = f2b(acc[t][3]);
                const int chunk = m >> 5, sl = (m >> 4) & 1, cl = m & 15;
                const int ksl = p0 >> 5, gl = (p0 >> 3) & 3, el0 = p0 & 7;
                *(u16x4*)&kpm[(size_t)(bb*HEADS + hh)*SEQ*DIM
                    + (size_t)((chunk*8 + sl*4 + ksl)*64 + gl*16 + cl)*8 + el0] = o;
            }
        }
    } else {
        // ---- normal: V half (weight rows 1024..2047 of wkv) ----
        const int mt = by*4 + wave;
        #pragma unroll
        for (int ks = 0; ks < 4; ++ks) {
            bf16x8 af = *(const bf16x8*)(yn + (((size_t)(mt*4 + ks)) << 9) + lane*8);
            #pragma unroll
            for (int t = 0; t < 4; ++t) {
                const int nt = 64 + (bx - 32)*4 + t;
                bf16x8 wf = *(const bf16x8*)(wkv + (((size_t)(nt*4 + ks)) << 9) + lane*8);
                acc[t] = __builtin_amdgcn_mfma_f32_16x16x32_bf16(af, wf, acc[t], 0, 0, 0);
            }
        }
        const int m_row0 = by*64 + wave*16 + g*4;       // seq row, r walks +1
        const int bb = m_row0 >> 10;
        const int m0 = m_row0 & 1023;
        const int chunk = m0 >> 5, gl = (m0 >> 3) & 3, el0 = m0 & 7;
        #pragma unroll
        for (int t = 0; t < 4; ++t) {
            const int p = (bx - 32)*64 + t*16 + c16;
            const int hh = p >> 7, pp = p & 127, pcl = pp >> 4, cl = pp & 15;
            u16x4 o;
            o[0] = f2b(acc[t][0]); o[1] = f2b(acc[t][1]);
            o[2] = f2b(acc[t][2]); o[3] = f2b(acc[t][3]);
            *(u16x4*)&vpm[(size_t)(bb*HEADS + hh)*SEQ*DIM
                + (size_t)((chunk*8 + pcl)*64 + gl*16 + cl)*8 + el0] = o;
        }
    }
}

// ---------------- Flash attention (round-13 proven): 8 waves x 16 q-rows, dbuf LDS K/V ----------------
__global__ __launch_bounds__(512)
void attn_kernel(const unsigned short* __restrict__ qbuf,  // (B,H,N,P) pre-scaled
                 const unsigned short* __restrict__ kperm, // per bh: [chunk][frag 4096]
                 const unsigned short* __restrict__ vperm, // per bh: [chunk][frag 4096]
                 unsigned short* __restrict__ obuf)        // PA(1024) over rows (B*SEQ)
{
    __shared__ unsigned short kbuf[2][4096];   // 8KB per chunk
    __shared__ unsigned short vbuf[2][4096];
    __shared__ unsigned short pls[8][640];     // per wave: 16 rows x 40

    const int lane = threadIdx.x & 63;
    const int wave = threadIdx.x >> 6;         // 0..7
    const int g    = lane >> 4;
    const int c16  = lane & 15;

    // XCD swizzle: all 8 q-blocks of one bh land on the same XCD (j%8)
    const int j    = blockIdx.x;
    const int bh   = (j & 7) * 8 + (j >> 6);
    const int nblk = (j >> 3) & 7;
    const int n0   = nblk * 128 + wave * 16;
    const int bb   = bh >> 3, hh = bh & 7;

    const unsigned short* Q  = qbuf  + (size_t)bh * SEQ * DIM;
    const unsigned short* Kb = kperm + (size_t)bh * SEQ * DIM;
    const unsigned short* Vb = vperm + (size_t)bh * SEQ * DIM;

    // stage chunk 0: wave w covers K segment w and V segment w (1 load each)
    gl_lds16(Kb + wave*512 + lane*8, &kbuf[0][wave*512]);
    gl_lds16(Vb + wave*512 + lane*8, &vbuf[0][wave*512]);

    bf16x8 qf[4];
    #pragma unroll
    for (int ks = 0; ks < 4; ++ks)
        qf[ks] = *(const bf16x8*)(Q + (size_t)(n0 + c16)*DIM + ks*32 + g*8);

    f32x4 oacc[8];
    #pragma unroll
    for (int pc = 0; pc < 8; ++pc) oacc[pc] = (f32x4){0.f,0.f,0.f,0.f};
    float mi = 8.0f;              // row-uniform initial max guess (exp2 domain)
    float li0 = 0.f, li1 = 0.f;

    __syncthreads();   // chunk 0 staged

    int cur = 0;
    for (int it = 0; it < 32; ++it, cur ^= 1) {
        // ---- stage chunk it+1 (async; drains at the end-of-iter barrier) ----
        if (it != 31) {
            const unsigned short* Ks = Kb + (size_t)(it + 1) * 4096;
            const unsigned short* Vs = Vb + (size_t)(it + 1) * 4096;
            gl_lds16(Ks + wave*512 + lane*8, &kbuf[cur ^ 1][wave*512]);
            gl_lds16(Vs + wave*512 + lane*8, &vbuf[cur ^ 1][wave*512]);
        }

        // ---- K fragments + QK^T ----
        bf16x8 kf[2][4];
        #pragma unroll
        for (int s = 0; s < 2; ++s)
            #pragma unroll
            for (int ks = 0; ks < 4; ++ks)
                kf[s][ks] = *(const bf16x8*)&kbuf[cur][(s*4 + ks)*512 + lane*8];

        f32x4 st[2];
        #pragma unroll
        for (int s = 0; s < 2; ++s) {
            f32x4 a = (f32x4){0.f,0.f,0.f,0.f};
            #pragma unroll
            for (int ks = 0; ks < 4; ++ks)
                a = __builtin_amdgcn_mfma_f32_16x16x32_bf16(kf[s][ks], qf[ks], a, 0, 0, 0);
            st[s] = a;
        }

        // ---- V fragments (issued early; consumed after softmax) ----
        bf16x8 vf[8];
        #pragma unroll
        for (int pc = 0; pc < 8; ++pc)
            vf[pc] = *(const bf16x8*)&vbuf[cur][(pc*64 + lane)*8];

        // ---- softmax (per-lane common path; rescale ~never taken) ----
        float cmax = st[0][0];
        cmax = fmaxf(cmax, st[0][1]); cmax = fmaxf(cmax, st[0][2]); cmax = fmaxf(cmax, st[0][3]);
        cmax = fmaxf(cmax, st[1][0]); cmax = fmaxf(cmax, st[1][1]);
        cmax = fmaxf(cmax, st[1][2]); cmax = fmaxf(cmax, st[1][3]);

        if (!__all(cmax - mi <= 8.0f)) {
            float rmax = cmax;
            rmax = fmaxf(rmax, __shfl_xor(rmax, 16));
            rmax = fmaxf(rmax, __shfl_xor(rmax, 32));
            const float mnew  = fmaxf(mi, rmax);
            const float alpha = exp2f(mi - mnew);
            mi = mnew;
            li0 *= alpha; li1 *= alpha;
            float ar[4];
            #pragma unroll
            for (int r = 0; r < 4; ++r) ar[r] = __shfl(alpha, g*4 + r);
            #pragma unroll
            for (int pc = 0; pc < 8; ++pc)
                #pragma unroll
                for (int r = 0; r < 4; ++r) oacc[pc][r] *= ar[r];
        }

        uint2 pw[2];
        {
            float p0 = exp2f(st[0][0] - mi), p1 = exp2f(st[0][1] - mi);
            float p2 = exp2f(st[0][2] - mi), p3 = exp2f(st[0][3] - mi);
            float p4 = exp2f(st[1][0] - mi), p5 = exp2f(st[1][1] - mi);
            float p6 = exp2f(st[1][2] - mi), p7 = exp2f(st[1][3] - mi);
            li0 += (p0 + p1) + (p2 + p3);
            li1 += (p4 + p5) + (p6 + p7);
            pw[0].x = cvt_pk_bf16(p0, p1); pw[0].y = cvt_pk_bf16(p2, p3);
            pw[1].x = cvt_pk_bf16(p4, p5); pw[1].y = cvt_pk_bf16(p6, p7);
        }

        unsigned short* pbase = &pls[wave][0];
        *(uint2*)(pbase + c16*40 + 0*16 + g*4) = pw[0];
        *(uint2*)(pbase + c16*40 + 1*16 + g*4) = pw[1];

        // ---- PV ----
        bf16x8 pa = *(const bf16x8*)(pbase + c16*40 + g*8);
        #pragma unroll
        for (int pc = 0; pc < 8; ++pc)
            oacc[pc] = __builtin_amdgcn_mfma_f32_16x16x32_bf16(pa, vf[pc], oacc[pc], 0, 0, 0);

        __syncthreads();   // stage(it+1) drained + all waves done with buf[cur]
    }

    float li = li0 + li1;
    li += __shfl_xor(li, 16);
    li += __shfl_xor(li, 32);
    float lr[4];
    #pragma unroll
    for (int r = 0; r < 4; ++r) lr[r] = 1.f / __shfl(li, g*4 + r);
    #pragma unroll
    for (int pc = 0; pc < 8; ++pc)
        #pragma unroll
        for (int r = 0; r < 4; ++r) {
            const int row = bb*SEQ + n0 + g*4 + r;
            const int k   = hh*DIM + pc*16 + c16;
            obuf[pa_idx(row, k, INNER)] = f2b(oacc[pc][r] * lr[r]);
        }
}

// ---------------- proj GEMM + bias + ls1*resid + LayerNorm fused ----------------
__global__ __launch_bounds__(256)
void projln_kernel(const unsigned short* __restrict__ A,   // ob PA(1024)
                   const unsigned short* __restrict__ W,   // wpr PA(1024), 128 rows
                   const float* __restrict__ bias,         // proj_b
                   const float* __restrict__ gamma,        // ls1_gamma
                   const float* __restrict__ xres,         // x (f32)
                   float* __restrict__ x1,                 // out: residual (f32)
                   const float* __restrict__ lnw, const float* __restrict__ lnb,
                   unsigned short* __restrict__ hin)       // out: PA(128)
{
    __shared__ float part[4][16][2];

    const int lane = threadIdx.x & 63;
    const int wave = threadIdx.x >> 6;
    const int g    = lane >> 4;
    const int c16  = lane & 15;
    const int mt   = blockIdx.x;

    f32x4 acc[2];
    acc[0] = (f32x4){0.f,0.f,0.f,0.f};
    acc[1] = (f32x4){0.f,0.f,0.f,0.f};

    #pragma unroll 4
    for (int ks = 0; ks < 32; ++ks) {
        bf16x8 af = *(const bf16x8*)(A + (((size_t)(mt*32 + ks)) << 9) + lane*8);
        #pragma unroll
        for (int t = 0; t < 2; ++t) {
            bf16x8 wf = *(const bf16x8*)(W + (((size_t)((wave*2 + t)*32 + ks)) << 9) + lane*8);
            acc[t] = __builtin_amdgcn_mfma_f32_16x16x32_bf16(af, wf, acc[t], 0, 0, 0);
        }
    }

    float v[2][4];
    #pragma unroll
    for (int t = 0; t < 2; ++t) {
        const int col = wave*32 + t*16 + c16;
        const float bb = bias[col], gg = gamma[col];
        #pragma unroll
        for (int r = 0; r < 4; ++r) {
            const int row = mt*16 + g*4 + r;
            const float xv = xres[(size_t)row*DIM + col];
            v[t][r] = xv + (acc[t][r] + bb) * gg;
            x1[(size_t)row*DIM + col] = v[t][r];
        }
    }
    #pragma unroll
    for (int r = 0; r < 4; ++r) {
        float s = v[0][r] + v[1][r];
        float q = v[0][r]*v[0][r] + v[1][r]*v[1][r];
        #pragma unroll
        for (int off = 1; off < 16; off <<= 1) {
            s += __shfl_xor(s, off);
            q += __shfl_xor(q, off);
        }
        if (c16 == 0) { part[wave][g*4+r][0] = s; part[wave][g*4+r][1] = q; }
    }
    __syncthreads();

    #pragma unroll
    for (int r = 0; r < 4; ++r) {
        const int lr = g*4 + r;
        const float s = part[0][lr][0] + part[1][lr][0] + part[2][lr][0] + part[3][lr][0];
        const float q = part[0][lr][1] + part[1][lr][1] + part[2][lr][1] + part[3][lr][1];
        const float mu  = s * (1.0f/128.0f);
        const float var = q * (1.0f/128.0f) - mu*mu;
        const float rs  = rsqrtf(var + 1e-5f);
        const int row = mt*16 + lr;
        #pragma unroll
        for (int t = 0; t < 2; ++t) {
            const int col = wave*32 + t*16 + c16;
            const float hv = (v[t][r] - mu) * rs * lnw[col] + lnb[col];
            hin[pa_idx(row, col, 128)] = f2b(hv);
        }
    }
}

// ---------------- fc1 + relu + fc2 + bias + ls2*resid fused ----------------
__global__ __launch_bounds__(256)
void fc_kernel(const unsigned short* __restrict__ hin,  // PA(128)
               const unsigned short* __restrict__ W1,   // PA(128), 512 rows
               const float* __restrict__ b1,
               const unsigned short* __restrict__ W2,   // PA(512), 128 rows
               const float* __restrict__ b2,
               const float* __restrict__ gamma2,        // ls2
               const float* __restrict__ x1,            // f32 residual
               float* __restrict__ dout)
{
    __shared__ unsigned short h[16][520];   // 512 + 8 pad

    const int lane = threadIdx.x & 63;
    const int wave = threadIdx.x >> 6;
    const int g    = lane >> 4;
    const int c16  = lane & 15;
    const int mt   = blockIdx.x;

    f32x4 a1[8];
    #pragma unroll
    for (int t = 0; t < 8; ++t) a1[t] = (f32x4){0.f,0.f,0.f,0.f};
    #pragma unroll
    for (int ks = 0; ks < 4; ++ks) {
        bf16x8 af = *(const bf16x8*)(hin + (((size_t)(mt*4 + ks)) << 9) + lane*8);
        #pragma unroll
        for (int t = 0; t < 8; ++t) {
            const int nt = wave*8 + t;
            bf16x8 wf = *(const bf16x8*)(W1 + (((size_t)(nt*4 + ks)) << 9) + lane*8);
            a1[t] = __builtin_amdgcn_mfma_f32_16x16x32_bf16(af, wf, a1[t], 0, 0, 0);
        }
    }
    #pragma unroll
    for (int t = 0; t < 8; ++t) {
        const int col = wave*128 + t*16 + c16;
        const float bb = b1[col];
        #pragma unroll
        for (int r = 0; r < 4; ++r)
            h[g*4 + r][col] = f2b(fmaxf(a1[t][r] + bb, 0.f));
    }
    __syncthreads();

    f32x4 a2[2];
    a2[0] = (f32x4){0.f,0.f,0.f,0.f};
    a2[1] = (f32x4){0.f,0.f,0.f,0.f};
    #pragma unroll 4
    for (int ks = 0; ks < 16; ++ks) {
        bf16x8 af = *(const bf16x8*)&h[c16][ks*32 + g*8];
        #pragma unroll
        for (int t = 0; t < 2; ++t) {
            const int nt = wave*2 + t;
            bf16x8 wf = *(const bf16x8*)(W2 + (((size_t)(nt*16 + ks)) << 9) + lane*8);
            a2[t] = __builtin_amdgcn_mfma_f32_16x16x32_bf16(af, wf, a2[t], 0, 0, 0);
        }
    }
    #pragma unroll
    for (int t = 0; t < 2; ++t) {
        const int col = wave*32 + t*16 + c16;
        const float bb = b2[col], gg = gamma2[col];
        #pragma unroll
        for (int r = 0; r < 4; ++r) {
            const int row = mt*16 + g*4 + r;
            dout[(size_t)row*DIM + col] = x1[(size_t)row*DIM + col] + (a2[t][r] + bb) * gg;
        }
    }
}

// ---------------- launch ----------------
extern "C" void kernel_launch(void* const* d_in, const int* in_sizes, int n_in,
                              void* d_out, int out_size, void* d_ws, size_t ws_size,
                              hipStream_t stream)
{
    const float* x         = (const float*)d_in[0];
    const float* y         = (const float*)d_in[1];
    const float* norm_x_w  = (const float*)d_in[2];
    const float* norm_x_b  = (const float*)d_in[3];
    const float* norm_y_w  = (const float*)d_in[4];
    const float* norm_y_b  = (const float*)d_in[5];
    const float* q_w       = (const float*)d_in[6];
    const float* kv_w      = (const float*)d_in[7];
    const float* proj_w    = (const float*)d_in[8];
    const float* proj_b    = (const float*)d_in[9];
    const float* ls1_gamma = (const float*)d_in[10];
    const float* norm_o_w  = (const float*)d_in[11];
    const float* norm_o_b  = (const float*)d_in[12];
    const float* fc1_w     = (const float*)d_in[13];
    const float* fc1_b     = (const float*)d_in[14];
    const float* fc2_w     = (const float*)d_in[15];
    const float* fc2_b     = (const float*)d_in[16];
    const float* ls2_gamma = (const float*)d_in[17];

    char* ws = (char*)d_ws;
    size_t off = 0;
    auto alloc = [&](size_t bytes) {
        void* p = ws + off;
        off += (bytes + 255) & ~(size_t)255;
        return p;
    };
    unsigned short* xn  = (unsigned short*)alloc((size_t)ROWS*DIM*2);
    unsigned short* yn  = (unsigned short*)alloc((size_t)ROWS*DIM*2);
    unsigned short* qb  = (unsigned short*)alloc((size_t)ROWS*INNER*2);
    unsigned short* kpm = (unsigned short*)alloc((size_t)ROWS*INNER*2);
    unsigned short* vpm = (unsigned short*)alloc((size_t)ROWS*INNER*2);
    unsigned short* ob  = (unsigned short*)alloc((size_t)ROWS*INNER*2);
    float*          x1  = (float*)alloc((size_t)ROWS*DIM*4);
    unsigned short* hin = (unsigned short*)alloc((size_t)ROWS*DIM*2);
    unsigned short* wq   = (unsigned short*)alloc((size_t)INNER*DIM*2);
    unsigned short* wkv  = (unsigned short*)alloc((size_t)2*INNER*DIM*2);
    unsigned short* wpr  = (unsigned short*)alloc((size_t)DIM*INNER*2);
    unsigned short* wf1  = (unsigned short*)alloc((size_t)HIDDEN*DIM*2);
    unsigned short* wf2  = (unsigned short*)alloc((size_t)DIM*HIDDEN*2);

    // 0) convert + permute all weights (one launch)
    cvt_all_kernel<<<dim3(320), 256, 0, stream>>>(
        q_w, wq, kv_w, wkv, proj_w, wpr, fc1_w, wf1, fc2_w, wf2);

    // 1) LayerNorms of x and y -> PA(128)
    ln_dual_kernel<<<dim3(ROWS/4, 2), 256, 0, stream>>>(
        x, norm_x_w, norm_x_b, xn, y, norm_y_w, norm_y_b, yn);

    // 2) q + kv projections in one launch (8B vectorized scatter stores)
    qkv_kernel<<<dim3(48, ROWS/64), 256, 0, stream>>>(xn, yn, wq, wkv, qb, kpm, vpm);

    // 3) attention -> ob in PA(1024); 512 blocks x 8 waves (round-13 proven kernel)
    attn_kernel<<<dim3(512), 512, 0, stream>>>(qb, kpm, vpm, ob);

    // 4) proj + bias + ls1*resid + LN -> x1 (f32) and hin (PA 128)
    projln_kernel<<<dim3(ROWS/16), 256, 0, stream>>>(
        ob, wpr, proj_b, ls1_gamma, x, x1, norm_o_w, norm_o_b, hin);

    // 5) fc1 + relu + fc2 + bias + ls2*resid -> d_out (f32)
    fc_kernel<<<dim3(ROWS/16), 256, 0, stream>>>(
        hin, wf1, fc1_b, wf2, fc2_b, ls2_gamma, x1, (float*)d_out);
}